// Round 4
// baseline (1453.349 us; speedup 1.0000x reference)
//
#include <hip/hip_runtime.h>
#include <hip/hip_bf16.h>

#define N_VOX 200000
#define KOFF 27
#define PPK 100000
#define NPAIRS (KOFF * PPK)                       // 2,700,000
#define C 64
#define BN_EPS 1e-5f

#define BSHIFT 9                                   // bucket target = 512 pairs
#define NB ((NPAIRS + (1 << BSHIFT) - 1) >> BSHIFT) // 5274 buckets
#define NCELL (NB * KOFF)                          // 142,398 (bucket,k) cells
#define MAXP 640                                   // pairs/bucket cap (512 + max run ~45)
#define MAXV 112                                   // voxels/bucket cap (avg ~38)
#define OSTRIDE 67                                 // LDS out-tile stride (odd: no bank aliasing)

typedef __bf16 bf16x8 __attribute__((ext_vector_type(8)));
typedef __bf16 bf16x4 __attribute__((ext_vector_type(4)));
typedef float f32x4 __attribute__((ext_vector_type(4)));

// ---------------------------------------------------------------------------
// features fp32 -> bf16 (RNE), vectorized.
// ---------------------------------------------------------------------------
__global__ __launch_bounds__(256)
void convert_features(const float* __restrict__ f, __bf16* __restrict__ fb)
{
    const size_t total4 = (size_t)N_VOX * C / 4;
    const size_t i = (size_t)blockIdx.x * blockDim.x + threadIdx.x;
    if (i >= total4) return;
    const float4 v = ((const float4*)f)[i];
    bf16x4 o;
    o.x = (__bf16)v.x; o.y = (__bf16)v.y; o.z = (__bf16)v.z; o.w = (__bf16)v.w;
    ((bf16x4*)fb)[i] = o;
}

// ---------------------------------------------------------------------------
// weight [k][cin][cout] fp32 -> wt [k][cout][cin] bf16 (transposed for B-frags).
// ---------------------------------------------------------------------------
__global__ __launch_bounds__(256)
void convert_weight(const float* __restrict__ w, __bf16* __restrict__ wt)
{
    const int k = blockIdx.x;
    const float* W = w + (size_t)k * C * C;
    __bf16* Wt = wt + (size_t)k * C * C;
    for (int idx = threadIdx.x; idx < C * C; idx += 256) {
        const int ci = idx >> 6, co = idx & 63;
        Wt[co * C + ci] = (__bf16)W[idx];
    }
}

// ---------------------------------------------------------------------------
// Pass 1: per-voxel histogram of out_idx (int atomics).
// ---------------------------------------------------------------------------
__global__ __launch_bounds__(256)
void hist_vox(const int* __restrict__ out_idx, int* __restrict__ cnt)
{
    const int i = blockIdx.x * 256 + threadIdx.x;
    if (i < NPAIRS) atomicAdd(&cnt[out_idx[i]], 1);
}

// ---------------------------------------------------------------------------
// Generic exclusive-scan (3 kernels, n <= 256*1024).
// ---------------------------------------------------------------------------
__global__ __launch_bounds__(256)
void scan_block_sums(const int* __restrict__ src, int n, int* __restrict__ bsum)
{
    __shared__ int s[256];
    const int t = threadIdx.x;
    const int i0 = blockIdx.x * 1024 + t * 4;
    int v = 0;
#pragma unroll
    for (int j = 0; j < 4; ++j) { const int i = i0 + j; if (i < n) v += src[i]; }
    s[t] = v;
    __syncthreads();
    for (int d = 128; d > 0; d >>= 1) {
        if (t < d) s[t] += s[t + d];
        __syncthreads();
    }
    if (t == 0) bsum[blockIdx.x] = s[0];
}

__global__ __launch_bounds__(256)
void scan_base(const int* __restrict__ bsum, int* __restrict__ bbase, int nblk)
{
    __shared__ int s[256];
    const int t = threadIdx.x;
    const int v = (t < nblk) ? bsum[t] : 0;
    s[t] = v;
    for (int d = 1; d < 256; d <<= 1) {
        __syncthreads();
        const int x = (t >= d) ? s[t - d] : 0;
        __syncthreads();
        s[t] += x;
    }
    if (t < nblk) bbase[t] = s[t] - v;
}

__global__ __launch_bounds__(256)
void scan_write(const int* __restrict__ src, int n, const int* __restrict__ bbase,
                int* __restrict__ offs, int* __restrict__ cursor)
{
    __shared__ int s[256];
    const int t = threadIdx.x;
    const int i0 = blockIdx.x * 1024 + t * 4;
    int v[4]; int local = 0;
#pragma unroll
    for (int j = 0; j < 4; ++j) {
        const int i = i0 + j;
        v[j] = (i < n) ? src[i] : 0;
        local += v[j];
    }
    s[t] = local;
    for (int d = 1; d < 256; d <<= 1) {
        __syncthreads();
        const int x = (t >= d) ? s[t - d] : 0;
        __syncthreads();
        s[t] += x;
    }
    int run = s[t] - local + bbase[blockIdx.x];
#pragma unroll
    for (int j = 0; j < 4; ++j) {
        const int i = i0 + j;
        if (i < n) {
            offs[i] = run;
            if (cursor) cursor[i] = run;
            run += v[j];
        }
    }
}

// ---------------------------------------------------------------------------
// Pass 2: first voxel of each bucket (bucket = offs[v]>>BSHIFT). Buckets are
// voxel-intervals since offs is monotone; every bucket is hit because the max
// run (~45, Poisson-13.5 tail) is far below the 512-pair bucket span.
// ---------------------------------------------------------------------------
__global__ __launch_bounds__(256)
void bucket_starts(const int* __restrict__ offs, int* __restrict__ bucket_v0)
{
    const int v = blockIdx.x * 256 + threadIdx.x;
    if (v < N_VOX) atomicMin(&bucket_v0[offs[v] >> BSHIFT], v);
}

// ---------------------------------------------------------------------------
// Pass 3: histogram over (bucket,k) cells.
// ---------------------------------------------------------------------------
__global__ __launch_bounds__(256)
void cell_hist(const int* __restrict__ out_idx, const int* __restrict__ offs,
               int* __restrict__ cellCnt)
{
    const int i = blockIdx.x * 256 + threadIdx.x;
    if (i >= NPAIRS) return;
    const int v = out_idx[i];
    const int b = offs[v] >> BSHIFT;
    const int k = i / PPK;
    atomicAdd(&cellCnt[b * KOFF + k], 1);
}

// ---------------------------------------------------------------------------
// Pass 4: scatter pair metadata into (bucket,k)-sorted order. Only metadata
// moves (4B + 1B per pair) — no partial features.
// ---------------------------------------------------------------------------
__global__ __launch_bounds__(256)
void scatter_pairs(const int* __restrict__ in_idx, const int* __restrict__ out_idx,
                   const int* __restrict__ offs, const int* __restrict__ bucket_v0,
                   int* __restrict__ cursor, int* __restrict__ sorted_in,
                   unsigned char* __restrict__ sorted_vl)
{
    const int i = blockIdx.x * 256 + threadIdx.x;
    if (i >= NPAIRS) return;
    const int v = out_idx[i];
    const int b = offs[v] >> BSHIFT;
    const int k = i / PPK;
    const int pos = atomicAdd(&cursor[b * KOFF + k], 1);
    sorted_in[pos] = in_idx[i];
    const int vl = v - bucket_v0[b];           // >= 0 by construction
    sorted_vl[pos] = (unsigned char)((vl < 255) ? vl : 255);
}

// ---------------------------------------------------------------------------
// Owner-computes bucket GEMM. Block = bucket (~512 pairs, ~38 voxels).
//  - per k-segment, 16-row MFMA tasks; A-frags gathered directly from global
//    featb (each pair's 128B read once), B = W[k] cached in VGPRs per segment
//  - C-fragments accumulated into fp32 LDS out-tile via ds_add_f32
//  - epilogue: plain coalesced stores of owned rows + fused BN stats
// No fp32 global atomics anywhere.
// ---------------------------------------------------------------------------
__global__ __launch_bounds__(256)
void gemm_bucket(const __bf16* __restrict__ featb, const __bf16* __restrict__ wtb,
                 const int* __restrict__ cellOffs, const int* __restrict__ bucket_v0,
                 const int* __restrict__ sorted_in, const unsigned char* __restrict__ sorted_vl,
                 float* __restrict__ out, float* __restrict__ stats)
{
    __shared__ int   s_in[MAXP];
    __shared__ unsigned char s_vl[MAXP];
    __shared__ float outT[MAXV * OSTRIDE];   // 30.0 KB fp32 accumulation tile
    __shared__ int   s_task[72];             // <= 27 + 640/16 = 67 tasks
    __shared__ int   s_ntask;
    __shared__ float s_red[512];

    const int b = blockIdx.x;
    const int t = threadIdx.x;
    const int lane = t & 63, wave = t >> 6;
    const int m16 = lane & 15, quad = lane >> 4;

    const int p0 = cellOffs[b * KOFF];
    const int pend = (b + 1 < NB) ? cellOffs[(b + 1) * KOFF] : NPAIRS;
    const int np = min(pend - p0, MAXP);
    const int v0 = bucket_v0[b];
    int v1 = (b + 1 < NB) ? bucket_v0[b + 1] : N_VOX;
    v1 = min(v1, N_VOX);
    int nv = v1 - v0;
    if (nv <= 0) return;                     // degenerate (never in practice)
    nv = min(nv, MAXV);

    // stage metadata (coalesced: sorted arrays are contiguous per bucket)
    for (int i = t; i < np; i += 256) {
        s_in[i] = sorted_in[p0 + i];
        s_vl[i] = sorted_vl[p0 + i];
    }
    for (int i = t; i < nv * OSTRIDE; i += 256) outT[i] = 0.f;
    if (t == 0) {
        int ntk = 0, prev = 0;
        for (int k = 0; k < KOFF; ++k) {
            int e = ((k + 1 < KOFF) ? cellOffs[b * KOFF + k + 1] : pend) - p0;
            e = min(e, np);
            for (int r = min(prev, np); r < e; r += 16)
                s_task[ntk++] = (k << 20) | (r << 10) | min(e, r + 16);
            prev = e;
        }
        s_ntask = ntk;
    }
    __syncthreads();

    const int ntask = s_ntask;
    const int t0 = (ntask * wave) >> 2;       // contiguous ranges: consecutive
    const int t1 = (ntask * (wave + 1)) >> 2; // tasks often share k -> B reuse

    int kcur = -1;
    bf16x8 bf[4][2];
    for (int ti = t0; ti < t1; ++ti) {
        const int task = s_task[ti];
        const int k    = task >> 20;
        const int r0   = (task >> 10) & 1023;
        const int rend = task & 1023;
        if (k != kcur) {                      // wave-uniform branch
            const __bf16* W = wtb + (size_t)k * C * C;
#pragma unroll
            for (int nt = 0; nt < 4; ++nt) {
                bf[nt][0] = *(const bf16x8*)(W + (nt * 16 + m16) * C + quad * 8);
                bf[nt][1] = *(const bf16x8*)(W + (nt * 16 + m16) * C + 32 + quad * 8);
            }
            kcur = k;
        }
        const int row = r0 + m16;
        const bool av = row < rend;
        const int fi = av ? s_in[row] : 0;
        bf16x8 a0 = {}, a1 = {};
        if (av) {
            const __bf16* fp = featb + (size_t)fi * C + quad * 8;
            a0 = *(const bf16x8*)fp;
            a1 = *(const bf16x8*)(fp + 32);
        }
        f32x4 acc[4] = {};
#pragma unroll
        for (int nt = 0; nt < 4; ++nt) {
            acc[nt] = __builtin_amdgcn_mfma_f32_16x16x32_bf16(a0, bf[nt][0], acc[nt], 0, 0, 0);
            acc[nt] = __builtin_amdgcn_mfma_f32_16x16x32_bf16(a1, bf[nt][1], acc[nt], 0, 0, 0);
        }
        // C/D map: col = lane&15 (cout), row = quad*4 + reg (pair-row in frag)
        int vr[4];
#pragma unroll
        for (int reg = 0; reg < 4; ++reg) {
            const int r = r0 + quad * 4 + reg;
            vr[reg] = (r < rend) ? (int)s_vl[r] : 255;
        }
#pragma unroll
        for (int nt = 0; nt < 4; ++nt)
#pragma unroll
            for (int reg = 0; reg < 4; ++reg)
                if (vr[reg] < MAXV)
                    atomicAdd(&outT[vr[reg] * OSTRIDE + nt * 16 + m16], acc[nt][reg]);
    }
    __syncthreads();

    // owned rows: plain coalesced stores + fused BN stats (c == t&63 invariant)
    float s = 0.f, q = 0.f;
    for (int i = t; i < nv * C; i += 256) {
        const int r = i >> 6, c = i & 63;
        const float val = outT[r * OSTRIDE + c];
        out[(size_t)(v0 + r) * C + c] = val;
        s += val; q += val * val;
    }
    s_red[t] = s; s_red[256 + t] = q;
    __syncthreads();
    if (t < 64) {
        s = s_red[t] + s_red[64 + t] + s_red[128 + t] + s_red[192 + t];
        q = s_red[256 + t] + s_red[320 + t] + s_red[384 + t] + s_red[448 + t];
        unsafeAtomicAdd(&stats[t], s);
        unsafeAtomicAdd(&stats[64 + t], q);
    }
}

// ---------------------------------------------------------------------------
// Fallback (round-2): MFMA conv with fp32 atomic scatter + separate stats.
// ---------------------------------------------------------------------------
__global__ __launch_bounds__(256)
void conv_mfma_atomic(const __bf16* __restrict__ featb, const __bf16* __restrict__ wtb,
                      const int* __restrict__ in_idx, const int* __restrict__ out_idx,
                      float* __restrict__ out)
{
    constexpr int TP = 256;
    constexpr int STRIDE = 72;
    __shared__ __bf16 sA[TP * STRIDE];
    __shared__ int s_out[TP];
    const int k = blockIdx.y;
    const int tile_base = blockIdx.x * TP;
    const int t = threadIdx.x;
    const int lane = t & 63;
    const int wave = t >> 6;
    const int m16 = lane & 15;
    const int quad = lane >> 4;
    const __bf16* Wt = wtb + (size_t)k * C * C;
    bf16x8 bfrag[4][2];
#pragma unroll
    for (int nt = 0; nt < 4; ++nt)
#pragma unroll
        for (int kc = 0; kc < 2; ++kc)
            bfrag[nt][kc] = *(const bf16x8*)(Wt + (nt * 16 + m16) * C + kc * 32 + quad * 8);
    {
        const int pair = tile_base + t;
        s_out[t] = (pair < PPK) ? out_idx[(size_t)k * PPK + pair] : 0;
    }
    const int c8 = t & 7;
    const int r0 = t >> 3;
#pragma unroll
    for (int it = 0; it < 8; ++it) {
        const int r = r0 + it * 32;
        const int pair = tile_base + r;
        const int row = (pair < PPK) ? in_idx[(size_t)k * PPK + pair] : 0;
        const float4 v = *(const float4*)(featb + (size_t)row * C + c8 * 8);
        *(float4*)(sA + r * STRIDE + c8 * 8) = v;
    }
    __syncthreads();
    f32x4 acc[4][4] = {};
    const int mbase = wave * 64;
#pragma unroll
    for (int kc = 0; kc < 2; ++kc) {
        bf16x8 afrag[4];
#pragma unroll
        for (int mt = 0; mt < 4; ++mt)
            afrag[mt] = *(const bf16x8*)(sA + (mbase + mt * 16 + m16) * STRIDE + kc * 32 + quad * 8);
#pragma unroll
        for (int nt = 0; nt < 4; ++nt)
#pragma unroll
            for (int mt = 0; mt < 4; ++mt)
                acc[mt][nt] = __builtin_amdgcn_mfma_f32_16x16x32_bf16(
                    afrag[mt], bfrag[nt][kc], acc[mt][nt], 0, 0, 0);
    }
#pragma unroll
    for (int mt = 0; mt < 4; ++mt)
#pragma unroll
        for (int reg = 0; reg < 4; ++reg) {
            const int r = mbase + mt * 16 + quad * 4 + reg;
            const int pair = tile_base + r;
            if (pair < PPK) {
                float* orow = out + (size_t)s_out[r] * C + m16;
#pragma unroll
                for (int nt = 0; nt < 4; ++nt)
                    unsafeAtomicAdd(orow + nt * 16, acc[mt][nt][reg]);
            }
        }
}

__global__ __launch_bounds__(256)
void stats_kernel(const float* __restrict__ out, float* __restrict__ stats,
                  int rows_per_block)
{
    __shared__ float ssum[256];
    __shared__ float ssq[256];
    const int c = threadIdx.x & 63;
    const int sub = threadIdx.x >> 6;
    const int row0 = blockIdx.x * rows_per_block;
    const int row1 = min(row0 + rows_per_block, N_VOX);
    float s = 0.f, q = 0.f;
    for (int r = row0 + sub; r < row1; r += 4) {
        const float v = out[(size_t)r * C + c];
        s += v; q += v * v;
    }
    ssum[threadIdx.x] = s;
    ssq[threadIdx.x] = q;
    __syncthreads();
    if (sub == 0) {
        s = ssum[c] + ssum[64 + c] + ssum[128 + c] + ssum[192 + c];
        q = ssq[c] + ssq[64 + c] + ssq[128 + c] + ssq[192 + c];
        unsafeAtomicAdd(&stats[c], s);
        unsafeAtomicAdd(&stats[64 + c], q);
    }
}

// ---------------------------------------------------------------------------
// BN finalize + apply (conv bias cancels exactly under BN; never added).
// ---------------------------------------------------------------------------
__global__ void finalize_params(const float* __restrict__ stats,
                                const float* __restrict__ gamma,
                                const float* __restrict__ beta,
                                float* __restrict__ ss)
{
    const int c = threadIdx.x;
    const float inv_n = 1.0f / (float)N_VOX;
    const float mean = stats[c] * inv_n;
    const float var = stats[64 + c] * inv_n - mean * mean;
    const float scale = rsqrtf(var + BN_EPS) * gamma[c];
    ss[c] = scale;
    ss[64 + c] = beta[c] - mean * scale;
}

__global__ __launch_bounds__(256)
void norm_kernel(float* __restrict__ out, const float* __restrict__ ss)
{
    const size_t total4 = (size_t)N_VOX * C / 4;
    const size_t idx = (size_t)blockIdx.x * blockDim.x + threadIdx.x;
    if (idx >= total4) return;
    const int c4 = (int)(idx & 15);
    float4 v = ((const float4*)out)[idx];
    const float4 sc = ((const float4*)ss)[c4];
    const float4 sh = ((const float4*)(ss + 64))[c4];
    v.x = fmaxf(v.x * sc.x + sh.x, 0.f);
    v.y = fmaxf(v.y * sc.y + sh.y, 0.f);
    v.z = fmaxf(v.z * sc.z + sh.z, 0.f);
    v.w = fmaxf(v.w * sc.w + sh.w, 0.f);
    ((float4*)out)[idx] = v;
}

extern "C" void kernel_launch(void* const* d_in, const int* in_sizes, int n_in,
                              void* d_out, int out_size, void* d_ws, size_t ws_size,
                              hipStream_t stream)
{
    const float* features = (const float*)d_in[0];
    const float* weight   = (const float*)d_in[1];
    // d_in[2] = bias: cancels exactly under BatchNorm — unused.
    const float* gamma    = (const float*)d_in[3];
    const float* beta     = (const float*)d_in[4];
    const int*   in_idx   = (const int*)d_in[5];
    const int*   out_idx  = (const int*)d_in[6];
    float* out = (float*)d_out;

    // ---- workspace layout (256B-aligned) — total ~43.4 MB ----
    char* base = (char*)d_ws;
    size_t cur = 0;
    auto alloc = [&](size_t bytes) -> char* {
        char* p = base + cur;
        cur = (cur + bytes + 255) & ~(size_t)255;
        return p;
    };
    __bf16* featb   = (__bf16*)alloc((size_t)N_VOX * C * 2);     // 25.6 MB
    __bf16* wtb     = (__bf16*)alloc((size_t)KOFF * C * C * 2);  // 221 KB
    float*  stats   = (float*)alloc(128 * 4);
    float*  ss      = (float*)alloc(128 * 4);
    int*    cnt     = (int*)alloc((size_t)N_VOX * 4);            // 800 KB
    int*    offs    = (int*)alloc((size_t)N_VOX * 4);            // 800 KB
    int*    b_v0    = (int*)alloc((size_t)NB * 4);               // 21 KB
    int*    cellCnt = (int*)alloc((size_t)NCELL * 4);            // 570 KB
    int*    cellOff = (int*)alloc((size_t)NCELL * 4);
    int*    cursor2 = (int*)alloc((size_t)NCELL * 4);
    int*    bsum    = (int*)alloc(256 * 4);
    int*    bbase   = (int*)alloc(256 * 4);
    int*    s_in    = (int*)alloc((size_t)NPAIRS * 4);           // 10.8 MB
    unsigned char* s_vl = (unsigned char*)alloc((size_t)NPAIRS); // 2.7 MB
    const bool fast = (ws_size >= cur);

    const size_t total4 = (size_t)N_VOX * C / 4;
    const int nb_elem = (int)((total4 + 255) / 256);
    const int nb_pair = (NPAIRS + 255) / 256;     // 10547

    hipMemsetAsync(stats, 0, 128 * sizeof(float), stream);
    convert_features<<<nb_elem, 256, 0, stream>>>(features, featb);
    convert_weight<<<KOFF, 256, 0, stream>>>(weight, wtb);

    if (fast) {
        hipMemsetAsync(cnt, 0, (size_t)N_VOX * 4, stream);
        hipMemsetAsync(cellCnt, 0, (size_t)NCELL * 4, stream);
        hipMemsetAsync(b_v0, 0x7F, (size_t)NB * 4, stream);      // "infinity"

        hist_vox<<<nb_pair, 256, 0, stream>>>(out_idx, cnt);

        const int nsA = (N_VOX + 1023) / 1024;                   // 196
        scan_block_sums<<<nsA, 256, 0, stream>>>(cnt, N_VOX, bsum);
        scan_base<<<1, 256, 0, stream>>>(bsum, bbase, nsA);
        scan_write<<<nsA, 256, 0, stream>>>(cnt, N_VOX, bbase, offs, (int*)nullptr);

        bucket_starts<<<(N_VOX + 255) / 256, 256, 0, stream>>>(offs, b_v0);
        cell_hist<<<nb_pair, 256, 0, stream>>>(out_idx, offs, cellCnt);

        const int nsB = (NCELL + 1023) / 1024;                   // 140
        scan_block_sums<<<nsB, 256, 0, stream>>>(cellCnt, NCELL, bsum);
        scan_base<<<1, 256, 0, stream>>>(bsum, bbase, nsB);
        scan_write<<<nsB, 256, 0, stream>>>(cellCnt, NCELL, bbase, cellOff, cursor2);

        scatter_pairs<<<nb_pair, 256, 0, stream>>>(in_idx, out_idx, offs, b_v0,
                                                   cursor2, s_in, s_vl);

        gemm_bucket<<<NB, 256, 0, stream>>>(featb, wtb, cellOff, b_v0,
                                            s_in, s_vl, out, stats);
    } else {
        hipMemsetAsync(out, 0, (size_t)N_VOX * C * sizeof(float), stream);
        dim3 cgrid((PPK + 255) / 256, KOFF);
        conv_mfma_atomic<<<cgrid, 256, 0, stream>>>(featb, wtb, in_idx, out_idx, out);
        const int rpb = (N_VOX + 511) / 512;
        stats_kernel<<<512, 256, 0, stream>>>(out, stats, rpb);
    }

    finalize_params<<<1, 64, 0, stream>>>(stats, gamma, beta, ss);
    norm_kernel<<<nb_elem, 256, 0, stream>>>(out, ss);
}